// Round 1
// baseline (2515.292 us; speedup 1.0000x reference)
//
#include <hip/hip_runtime.h>
#include <math.h>

// FISTA, phase-split 4x, XCD-colocated, L3-atomic exchange — R18.
// Changes vs R17 (1365 us):
//  - THREADS 576 -> 512 (8 waves, 2/SIMD balanced). Wave 0 handles BOTH light
//    boundary rows (0 and 8, 3 tap-rows each); waves 1-7 handle rows
//    (w&3)*2+(w>>2) so per-SIMD tap-row load is {10,10,10,9} vs old {11,9,10,9}.
//  - 75 conv weights hoisted from LDS into VGPRs (iteration-invariant
//    addresses; 2 waves/SIMD -> 256-VGPR budget). LWG/LWCT dropped from LDS
//    (54.8 KB -> 33 KB).
//  - Stage 2: thread t<486 owns 8 CONSECUTIVE y elements (same cell, c,
//    pl-half) -> float4 LDS reads/writes for y/y_last; Wct hoisted to 24 regs
//    (relaid [c][ci][p] in ws). Arithmetic order identical to R17.
//  - Decentralized barrier: per-wave s_waitcnt vmcnt(0) + relaxed fetch_add
//    (target = 32*(iter+1): 8 waves x 4 blocks), ALL waves spin; 2
//    __syncthreads per iter instead of 4. Correctness: L3 serializes
//    (stores acked < own add issued < count observed < Ap loads); WAR audit
//    unchanged: block B's iter-k+2 Ap writes require count>=32*(k+2), which
//    requires every block A's k+1 adds, which follow A's k pre-pass reads.
//
// Phase decomposition (proven R2-R17): a[cell,co] = sum_{d(5x5),ci,p}
// y[cell+d,ci,p] W[d,ci,p,co]; block g sums its 16 phases -> partial a.
// Wave = output row; lane = (q=ci quadrant, p_local); q=3 lanes carry zero
// weights (y reads duplicate q=2: same-address broadcast, free).

#define ITERS 200
#define THREADS 512
// d_ws float offsets (footprint unchanged vs R17: ~593 KB)
#define WGOFF 0          // 19200: [g][t*3+co][lane], q=3 lanes zeroed
#define WCTOFF 19200     // 576: [c][ci][p]  (relaid for stage-2 reg hoist)
#define APOFF 19776      // 2 * 64 * 4 * 243 = 124416 (double-buffered)
#define CNTOFF 144192    // int offsets: 64 images x 64-int padding
// LDS float offsets
#define LY 0             // y: 3888 = 243 idx3 x 16 p_local
#define LYL 3888         // y_last: 3888
#define LA 7776          // a: 243
#define LXS 8019         // x image slice: 243
#define SMEMF 8262       // 33,048 B

template <int CTRL>
__device__ __forceinline__ float dpp_add(float x) {
  int moved = __builtin_amdgcn_update_dpp(0, __float_as_int(x), CTRL, 0xF, 0xF, true);
  return x + __int_as_float(moved);
}
// gfx9 wave64 sum -> lane 63. Proven R2-R17.
__device__ __forceinline__ float wave_sum64_to_lane63(float x) {
  x = dpp_add<0x111>(x);
  x = dpp_add<0x112>(x);
  x = dpp_add<0x114>(x);
  x = dpp_add<0x118>(x);
  x = dpp_add<0x142>(x);
  x = dpp_add<0x143>(x);
  return x;
}

// WG[((g*75 + t*3 + co))*64 + lane] = w_conv[8*th+ph][8*tw+pw][ci=q][co]
//   with lane=(q,pl), p = g*16+pl; q==3 -> 0 (dead quadrant).
// WCT2[c*192 + ci*64 + p] = (rh<5 && rw<5) ? w_ct[4-rh][4-rw][ci][c] : 0,
//   p = rh*8+rw.  (Same values as R17's Wct[(p*3+c)*3+ci], new layout.)
__global__ void k0_init(const float* __restrict__ w_conv,
                        const float* __restrict__ w_ct,
                        float* __restrict__ ws) {
  const int i = blockIdx.x * 256 + threadIdx.x;
  if (i < 19200) {
    const int lane = i & 63;
    const int rest = i >> 6;          // g*75 + t*3 + co
    const int g = rest / 75;
    const int tc = rest - 75 * g;
    const int t = tc / 3;
    const int co = tc - 3 * t;
    const int th = t / 5;
    const int tw = t - 5 * th;
    const int q = lane >> 4;
    const int pl = lane & 15;
    float v = 0.f;
    if (q < 3) {
      const int p = g * 16 + pl;
      const int ph = p >> 3;
      const int pw = p & 7;
      v = w_conv[(((8 * th + ph) * 40 + (8 * tw + pw)) * 3 + q) * 3 + co];
    }
    ws[WGOFF + i] = v;
  }
  if (i < 576) {
    const int p = i & 63;
    const int ci = (i >> 6) % 3;
    const int c = i / 192;
    const int rh = p >> 3;
    const int rw = p & 7;
    float v = 0.f;
    if (rh < 5 && rw < 5) v = w_ct[(((4 - rh) * 5 + (4 - rw)) * 3 + ci) * 3 + c];
    ws[WCTOFF + i] = v;
  }
  if (i < 4096) ((int*)ws)[CNTOFF + i] = 0;
}

__global__ __launch_bounds__(THREADS, 2) void fista_split(
    float* __restrict__ ws,
    const float* __restrict__ x, const float* __restrict__ lam,
    const float* __restrict__ b_conv, const float* __restrict__ b_ct,
    float* __restrict__ out) {
  __shared__ __align__(16) float smem[SMEMF];
  const int tid = threadIdx.x;
  const int blk = blockIdx.x;
  const int n = blk & 63;         // image  (XCD colocation: n, n+64, n+128,
  const int g = blk >> 6;         //  n+192 share blk%8)
  const int lane = tid & 63;
  const int wid = tid >> 6;       // wave index, 8 waves
  const int q = lane >> 4;        // ci quadrant (3 = dead)
  const int pl = lane & 15;
  const int ylane = ((q < 3) ? q : 2) * 16 + pl;  // q=3 dupes q=2: broadcast
  // Row permutation: waves 1-7 -> rows {2,4,6,1,3,5,7}; wave 0 -> rows 0 AND 8
  // (both 3-tap boundary rows). Per-SIMD (w&3) tap-row load: {10,10,10,9}.
  const int row0 = (wid & 3) * 2 + (wid >> 2);
  const int npass = (wid == 0) ? 2 : 1;

  int* __restrict__ cnt = (int*)ws + CNTOFF + n * 64;
  const float lam_n = lam[n];
  const float bcv = b_conv[tid % 3];   // pre-pass bias (used when tid<243)

  // ---- conv weights -> 75 VGPRs (iteration-invariant; same for both passes
  // of wave 0 since weights depend on (tap,lane) only) ----
  float wreg[75];
#pragma unroll
  for (int i = 0; i < 75; ++i) wreg[i] = ws[WGOFF + g * 4800 + i * 64 + lane];

  // ---- stage-2 per-thread constants: thread t<486 owns elements
  // e = 8t .. 8t+7  (same idx3 = t>>1, pl-half = t&1) ----
  const int idx3 = tid >> 1;
  const int cell = idx3 / 3;
  const int c = idx3 - 3 * cell;
  const int cb = 3 * cell;
  const int pbase = g * 16 + (tid & 1) * 8;
  float wctr[3][8];
  float bctc = 0.f;
  if (tid < 486) {
#pragma unroll
    for (int ci = 0; ci < 3; ++ci)
#pragma unroll
      for (int j = 0; j < 8; ++j)
        wctr[ci][j] = ws[WCTOFF + c * 192 + ci * 64 + pbase + j];
    bctc = b_ct[c];
  }

  // ---- stage LDS: zero y/y_last; copy x slice ----
  for (int i = tid; i < 7776; i += THREADS) smem[i] = 0.f;
  if (tid < 243) smem[LXS + tid] = x[n * 243 + tid];
  __syncthreads();

  float t = 1.0f;
#pragma unroll 1
  for (int iter = 0; iter < ITERS; ++iter) {
    // ===== stage 1: partial a over this block's 16 phases =====
#pragma unroll 1
    for (int pass = 0; pass < npass; ++pass) {
      const int oh = pass ? 8 : row0;
      float acc[27];               // [ow*3 + co]
#pragma unroll
      for (int k = 0; k < 27; ++k) acc[k] = 0.f;

#pragma unroll
      for (int th = 0; th < 5; ++th) {
        const int r = oh + th - 2;          // input row
        if (r >= 0 && r <= 8) {
          float rv[13];                     // y col (k-2), zero-padded
          rv[0] = 0.f; rv[1] = 0.f; rv[11] = 0.f; rv[12] = 0.f;
#pragma unroll
          for (int wc = 0; wc < 9; ++wc)
            rv[wc + 2] = smem[LY + r * 432 + wc * 48 + ylane];

#pragma unroll
          for (int tw = 0; tw < 5; ++tw) {
            const int tb = (th * 5 + tw) * 3;
            const float w0 = wreg[tb + 0];
            const float w1 = wreg[tb + 1];
            const float w2 = wreg[tb + 2];
#pragma unroll
            for (int ow = 0; ow < 9; ++ow) {
              const float y = rv[ow + tw];
              acc[ow * 3 + 0] += y * w0;
              acc[ow * 3 + 1] += y * w1;
              acc[ow * 3 + 2] += y * w2;
            }
          }
        }
      }

#pragma unroll
      for (int k = 0; k < 27; ++k) acc[k] = wave_sum64_to_lane63(acc[k]);
      if (lane == 63) {
        float* ap = ws + APOFF + ((((iter & 1) * 64 + n) * 4 + g) * 243) + oh * 27;
#pragma unroll
        for (int k = 0; k < 27; ++k)
          __hip_atomic_store(ap + k, acc[k], __ATOMIC_RELAXED,
                             __HIP_MEMORY_SCOPE_AGENT);
      }
    }

    // ===== decentralized barrier: per-wave drain + add, all-wave spin =====
    asm volatile("s_waitcnt vmcnt(0)" ::: "memory");  // own Ap stores acked at L3
    if (lane == 63)
      __hip_atomic_fetch_add(cnt, 1, __ATOMIC_RELAXED, __HIP_MEMORY_SCOPE_AGENT);
    {
      const int target = 32 * (iter + 1);   // 8 waves x 4 blocks
      while (__hip_atomic_load(cnt, __ATOMIC_RELAXED, __HIP_MEMORY_SCOPE_AGENT)
             < target)
        __builtin_amdgcn_s_sleep(2);
    }
    asm volatile("" ::: "memory");  // keep Ap loads below the spin

    // ===== pre-pass: a = sum_g Ap + b_conv -> LDS (atomic loads: L3-fresh) ====
    if (tid < 243) {
      const float* ap = ws + APOFF + ((iter & 1) * 64 + n) * 4 * 243;
      const float a0 = __hip_atomic_load(ap + tid, __ATOMIC_RELAXED,
                                         __HIP_MEMORY_SCOPE_AGENT);
      const float a1 = __hip_atomic_load(ap + 243 + tid, __ATOMIC_RELAXED,
                                         __HIP_MEMORY_SCOPE_AGENT);
      const float a2 = __hip_atomic_load(ap + 486 + tid, __ATOMIC_RELAXED,
                                         __HIP_MEMORY_SCOPE_AGENT);
      const float a3 = __hip_atomic_load(ap + 729 + tid, __ATOMIC_RELAXED,
                                         __HIP_MEMORY_SCOPE_AGENT);
      smem[LA + tid] = a0 + a1 + a2 + a3 + bcv;
    }
    __syncthreads();

    const float tn = (1.0f + sqrtf(1.0f + 4.0f * t * t)) * 0.5f;
    const float beta = (t - 1.0f) / tn;    // beta_0 = 0
    t = tn;

    // ===== stage 2: 8 consecutive elements per thread, vectorized =====
    const bool lastit = (iter == ITERS - 1);
    if (tid < 486) {
      float4* lyv  = (float4*)&smem[LY];
      float4* lylv = (float4*)&smem[LYL];
      const float a0 = smem[LA + cb + 0];
      const float a1 = smem[LA + cb + 1];
      const float a2 = smem[LA + cb + 2];
      const float r0 = smem[LXS + cb + 0] - a0;
      const float r1 = smem[LXS + cb + 1] - a1;
      const float r2 = smem[LXS + cb + 2] - a2;

      const float4 y0 = lyv[2 * tid];
      const float4 y1 = lyv[2 * tid + 1];
      const float yv[8] = {y0.x, y0.y, y0.z, y0.w, y1.x, y1.y, y1.z, y1.w};
      float yn[8];
#pragma unroll
      for (int j = 0; j < 8; ++j) {
        const float re = bctc + r0 * wctr[0][j] + r1 * wctr[1][j] + r2 * wctr[2][j];
        const float wvv = yv[j] - re;
        yn[j] = fmaxf(wvv - lam_n, 0.f) - fmaxf(-wvv - lam_n, 0.f);
      }

      if (!lastit) {
        const float4 l0 = lylv[2 * tid];
        const float4 l1 = lylv[2 * tid + 1];
        const float ylv[8] = {l0.x, l0.y, l0.z, l0.w, l1.x, l1.y, l1.z, l1.w};
        float4 s0, s1, m0, m1;
        s0.x = yn[0]; s0.y = yn[1]; s0.z = yn[2]; s0.w = yn[3];
        s1.x = yn[4]; s1.y = yn[5]; s1.z = yn[6]; s1.w = yn[7];
        m0.x = yn[0] + beta * (yn[0] - ylv[0]);
        m0.y = yn[1] + beta * (yn[1] - ylv[1]);
        m0.z = yn[2] + beta * (yn[2] - ylv[2]);
        m0.w = yn[3] + beta * (yn[3] - ylv[3]);
        m1.x = yn[4] + beta * (yn[4] - ylv[4]);
        m1.y = yn[5] + beta * (yn[5] - ylv[5]);
        m1.z = yn[6] + beta * (yn[6] - ylv[6]);
        m1.w = yn[7] + beta * (yn[7] - ylv[7]);
        lylv[2 * tid] = s0; lylv[2 * tid + 1] = s1;
        lyv[2 * tid]  = m0; lyv[2 * tid + 1]  = m1;
      } else {
        const int part = pbase >> 3;       // p>>3 constant over j
        const int qh = cell / 9;
        const int qw = cell - 9 * qh;
        const int ih = 8 * qh + part;
        float* op = out + ((n * 72 + ih) * 72 + 8 * qw) * 3 + c;
#pragma unroll
        for (int j = 0; j < 8; ++j) op[3 * j] = yn[j];
      }
    }
    __syncthreads();
  }
}

extern "C" void kernel_launch(void* const* d_in, const int* in_sizes, int n_in,
                              void* d_out, int out_size, void* d_ws, size_t ws_size,
                              hipStream_t stream) {
  const float* x      = (const float*)d_in[0];
  const float* lam    = (const float*)d_in[1];
  const float* w_conv = (const float*)d_in[2];
  const float* b_conv = (const float*)d_in[3];
  const float* w_ct   = (const float*)d_in[4];
  const float* b_ct   = (const float*)d_in[5];
  float* out = (float*)d_out;
  float* ws  = (float*)d_ws;  // needs ~593 KB (unchanged)

  hipLaunchKernelGGL(k0_init, dim3(80), dim3(256), 0, stream, w_conv, w_ct, ws);
  hipLaunchKernelGGL(fista_split, dim3(256), dim3(THREADS), 0, stream,
                     ws, x, lam, b_conv, b_ct, out);
}

// Round 2
// 1566.364 us; speedup vs baseline: 1.6058x; 1.6058x over previous
//
#include <hip/hip_runtime.h>
#include <math.h>

// FISTA, phase-split 4x, XCD-colocated, L3-atomic exchange — R19.
// R18 post-mortem: all-wave spin (8 spinners/block, 2048 waves on 64 counter
// lines) + 32 fetch_adds/counter was a 2x regression (VALUBusy 58->22%,
// FETCH doubled from spin loads, one 22.9ms outlier). R19 reverts the barrier
// to the R17-PROVEN centralized form and keeps R18's compute wins:
//  - 512 threads / 8 waves, 2/SIMD balanced; wave 0 does both 3-tap boundary
//    rows (0 and 8); per-SIMD tap-row load {10,10,10,9}.
//  - 75 conv weights in VGPRs (iteration-invariant), LWG dropped from LDS.
//  - Stage 2: 8 consecutive y elements/thread -> float4 LDS ops. Wct weights
//    stay in LDS (c-stride 200 = bank-spread; 6 ds_read_b128/thread/iter)
//    to keep stage-1 live VGPRs (75 wreg + 27 acc + 13 rv) under 128.
//  - Barrier: __syncthreads (drains all waves' vmcnt: Ap stores ACKED at L3)
//    -> tid0 RELAXED fetch_add + RELAXED spin (target 4*(iter+1)) -> sync ->
//    pre-pass (tid<243, relaxed atomic loads) -> sync -> stage2 -> sync.
// WAR audit (R17, unchanged): pre-pass(k) < end-barrier(k) < stage1(k+1) <
// add(k+1); spin(k+1) sees 4(k+2) => all blocks did pre-pass(k); only then
// stage1(k+2) rewrites buffer k&1.
//
// Phase decomposition (proven R2-R18): a[cell,co] = sum_{d(5x5),ci,p}
// y[cell+d,ci,p] W[d,ci,p,co]; block g sums its 16 phases -> partial a.
// Wave = output row; lane = (q=ci quadrant, p_local); q=3 lanes carry zero
// weights (y reads duplicate q=2: same-address broadcast, free).

#define ITERS 200
#define THREADS 512
// d_ws float offsets
#define WGOFF 0          // 19200: [g][t*3+co][lane], q=3 lanes zeroed
#define WCTOFF 19200     // 600: [c(stride 200)][ci*64][p]
#define APOFF 19800      // 2 * 64 * 4 * 243 = 124416 (double-buffered)
#define CNTOFF 144256    // int offsets: 64 images x 64-int padding
// LDS float offsets (float4-aligned regions)
#define LY 0             // y: 3888 = 243 idx3 x 16 p_local
#define LYL 3888         // y_last: 3888
#define LA 7776          // a: 243 (+1 pad)
#define LXS 8020         // x image slice: 243 (+1 pad)
#define LWCT 8264        // Wct: 600
#define SMEMF 8864       // 35,456 B

template <int CTRL>
__device__ __forceinline__ float dpp_add(float x) {
  int moved = __builtin_amdgcn_update_dpp(0, __float_as_int(x), CTRL, 0xF, 0xF, true);
  return x + __int_as_float(moved);
}
// gfx9 wave64 sum -> lane 63. Proven R2-R18.
__device__ __forceinline__ float wave_sum64_to_lane63(float x) {
  x = dpp_add<0x111>(x);
  x = dpp_add<0x112>(x);
  x = dpp_add<0x114>(x);
  x = dpp_add<0x118>(x);
  x = dpp_add<0x142>(x);
  x = dpp_add<0x143>(x);
  return x;
}

// WG[((g*75 + t*3 + co))*64 + lane] = w_conv[8*th+ph][8*tw+pw][ci=q][co]
//   with lane=(q,pl), p = g*16+pl; q==3 -> 0 (dead quadrant).
// WCT2[c*200 + ci*64 + p] = (rh<5 && rw<5) ? w_ct[4-rh][4-rw][ci][c] : 0,
//   p = rh*8+rw.  (c-stride 200: cross-lane bank spread in stage 2.)
__global__ void k0_init(const float* __restrict__ w_conv,
                        const float* __restrict__ w_ct,
                        float* __restrict__ ws) {
  const int i = blockIdx.x * 256 + threadIdx.x;
  if (i < 19200) {
    const int lane = i & 63;
    const int rest = i >> 6;          // g*75 + t*3 + co
    const int g = rest / 75;
    const int tc = rest - 75 * g;
    const int t = tc / 3;
    const int co = tc - 3 * t;
    const int th = t / 5;
    const int tw = t - 5 * th;
    const int q = lane >> 4;
    const int pl = lane & 15;
    float v = 0.f;
    if (q < 3) {
      const int p = g * 16 + pl;
      const int ph = p >> 3;
      const int pw = p & 7;
      v = w_conv[(((8 * th + ph) * 40 + (8 * tw + pw)) * 3 + q) * 3 + co];
    }
    ws[WGOFF + i] = v;
  }
  if (i < 600) {
    const int c = i / 200;
    const int rem = i - 200 * c;
    float v = 0.f;
    if (rem < 192) {
      const int ci = rem >> 6;
      const int p = rem & 63;
      const int rh = p >> 3;
      const int rw = p & 7;
      if (rh < 5 && rw < 5) v = w_ct[(((4 - rh) * 5 + (4 - rw)) * 3 + ci) * 3 + c];
    }
    ws[WCTOFF + i] = v;
  }
  if (i < 4096) ((int*)ws)[CNTOFF + i] = 0;
}

__global__ __launch_bounds__(THREADS, 2) void fista_split(
    float* __restrict__ ws,
    const float* __restrict__ x, const float* __restrict__ lam,
    const float* __restrict__ b_conv, const float* __restrict__ b_ct,
    float* __restrict__ out) {
  __shared__ __align__(16) float smem[SMEMF];
  const int tid = threadIdx.x;
  const int blk = blockIdx.x;
  const int n = blk & 63;         // image  (XCD colocation: n, n+64, n+128,
  const int g = blk >> 6;         //  n+192 share blk%8)
  const int lane = tid & 63;
  const int wid = tid >> 6;       // wave index, 8 waves
  const int q = lane >> 4;        // ci quadrant (3 = dead)
  const int pl = lane & 15;
  const int ylane = ((q < 3) ? q : 2) * 16 + pl;  // q=3 dupes q=2: broadcast
  // Row permutation: waves 1-7 -> rows {2,4,6,1,3,5,7}; wave 0 -> rows 0 AND 8
  // (both 3-tap boundary rows). Per-SIMD tap-row load: {10,10,10,9}.
  const int row0 = (wid & 3) * 2 + (wid >> 2);
  const int npass = (wid == 0) ? 2 : 1;

  int* __restrict__ cnt = (int*)ws + CNTOFF + n * 64;
  const float lam_n = lam[n];
  const float bcv = b_conv[tid % 3];   // pre-pass bias (used when tid<243)

  // ---- conv weights -> 75 VGPRs (iteration-invariant; same for both passes
  // of wave 0 since weights depend on (tap,lane) only) ----
  float wreg[75];
#pragma unroll
  for (int i = 0; i < 75; ++i) wreg[i] = ws[WGOFF + g * 4800 + i * 64 + lane];

  // ---- stage-2 per-thread constants: thread t<486 owns elements
  // e = 8t .. 8t+7  (same idx3 = t>>1, pl-half = t&1) ----
  const int idx3 = tid >> 1;
  const int cell = idx3 / 3;
  const int c = idx3 - 3 * cell;
  const int cb = 3 * cell;
  const int pbase = g * 16 + (tid & 1) * 8;
  const float bctc = (tid < 486) ? b_ct[c] : 0.f;

  // ---- stage LDS: zero y/y_last; copy x slice + Wct ----
  for (int i = tid; i < 7776; i += THREADS) smem[i] = 0.f;
  if (tid < 243) smem[LXS + tid] = x[n * 243 + tid];
  for (int i = tid; i < 600; i += THREADS) smem[LWCT + i] = ws[WCTOFF + i];
  __syncthreads();

  float t = 1.0f;
#pragma unroll 1
  for (int iter = 0; iter < ITERS; ++iter) {
    // ===== stage 1: partial a over this block's 16 phases =====
#pragma unroll 1
    for (int pass = 0; pass < npass; ++pass) {
      const int oh = pass ? 8 : row0;
      float acc[27];               // [ow*3 + co]
#pragma unroll
      for (int k = 0; k < 27; ++k) acc[k] = 0.f;

#pragma unroll
      for (int th = 0; th < 5; ++th) {
        const int r = oh + th - 2;          // input row
        if (r >= 0 && r <= 8) {
          float rv[13];                     // y col (k-2), zero-padded
          rv[0] = 0.f; rv[1] = 0.f; rv[11] = 0.f; rv[12] = 0.f;
#pragma unroll
          for (int wc = 0; wc < 9; ++wc)
            rv[wc + 2] = smem[LY + r * 432 + wc * 48 + ylane];

#pragma unroll
          for (int tw = 0; tw < 5; ++tw) {
            const int tb = (th * 5 + tw) * 3;
            const float w0 = wreg[tb + 0];
            const float w1 = wreg[tb + 1];
            const float w2 = wreg[tb + 2];
#pragma unroll
            for (int ow = 0; ow < 9; ++ow) {
              const float y = rv[ow + tw];
              acc[ow * 3 + 0] += y * w0;
              acc[ow * 3 + 1] += y * w1;
              acc[ow * 3 + 2] += y * w2;
            }
          }
        }
      }

#pragma unroll
      for (int k = 0; k < 27; ++k) acc[k] = wave_sum64_to_lane63(acc[k]);
      if (lane == 63) {
        float* ap = ws + APOFF + ((((iter & 1) * 64 + n) * 4 + g) * 243) + oh * 27;
#pragma unroll
        for (int k = 0; k < 27; ++k)
          __hip_atomic_store(ap + k, acc[k], __ATOMIC_RELAXED,
                             __HIP_MEMORY_SCOPE_AGENT);
      }
    }

    // ===== centralized barrier (R17-proven): one spinner, rest at s_barrier ==
    __syncthreads();               // compiler drains vmcnt: Ap stores acked at L3
    if (tid == 0) {
      __hip_atomic_fetch_add(cnt, 1, __ATOMIC_RELAXED, __HIP_MEMORY_SCOPE_AGENT);
      const int target = 4 * (iter + 1);
      while (__hip_atomic_load(cnt, __ATOMIC_RELAXED, __HIP_MEMORY_SCOPE_AGENT)
             < target)
        __builtin_amdgcn_s_sleep(1);
    }
    __syncthreads();

    // ===== pre-pass: a = sum_g Ap + b_conv -> LDS (atomic loads: L3-fresh) ====
    if (tid < 243) {
      const float* ap = ws + APOFF + ((iter & 1) * 64 + n) * 4 * 243;
      const float a0 = __hip_atomic_load(ap + tid, __ATOMIC_RELAXED,
                                         __HIP_MEMORY_SCOPE_AGENT);
      const float a1 = __hip_atomic_load(ap + 243 + tid, __ATOMIC_RELAXED,
                                         __HIP_MEMORY_SCOPE_AGENT);
      const float a2 = __hip_atomic_load(ap + 486 + tid, __ATOMIC_RELAXED,
                                         __HIP_MEMORY_SCOPE_AGENT);
      const float a3 = __hip_atomic_load(ap + 729 + tid, __ATOMIC_RELAXED,
                                         __HIP_MEMORY_SCOPE_AGENT);
      smem[LA + tid] = a0 + a1 + a2 + a3 + bcv;
    }
    __syncthreads();

    const float tn = (1.0f + sqrtf(1.0f + 4.0f * t * t)) * 0.5f;
    const float beta = (t - 1.0f) / tn;    // beta_0 = 0
    t = tn;

    // ===== stage 2: 8 consecutive elements per thread, vectorized =====
    const bool lastit = (iter == ITERS - 1);
    if (tid < 486) {
      float4* lyv  = (float4*)&smem[LY];
      float4* lylv = (float4*)&smem[LYL];
      const float a0 = smem[LA + cb + 0];
      const float a1 = smem[LA + cb + 1];
      const float a2 = smem[LA + cb + 2];
      const float r0 = smem[LXS + cb + 0] - a0;
      const float r1 = smem[LXS + cb + 1] - a1;
      const float r2 = smem[LXS + cb + 2] - a2;

      // Wct from LDS: [c*200 + ci*64 + pbase], 16B-aligned, 2-way max banks
      const float4 w0a = *(const float4*)&smem[LWCT + c * 200 +   0 + pbase];
      const float4 w0b = *(const float4*)&smem[LWCT + c * 200 +   4 + pbase];
      const float4 w1a = *(const float4*)&smem[LWCT + c * 200 +  64 + pbase];
      const float4 w1b = *(const float4*)&smem[LWCT + c * 200 +  68 + pbase];
      const float4 w2a = *(const float4*)&smem[LWCT + c * 200 + 128 + pbase];
      const float4 w2b = *(const float4*)&smem[LWCT + c * 200 + 132 + pbase];
      const float wct0[8] = {w0a.x, w0a.y, w0a.z, w0a.w, w0b.x, w0b.y, w0b.z, w0b.w};
      const float wct1[8] = {w1a.x, w1a.y, w1a.z, w1a.w, w1b.x, w1b.y, w1b.z, w1b.w};
      const float wct2[8] = {w2a.x, w2a.y, w2a.z, w2a.w, w2b.x, w2b.y, w2b.z, w2b.w};

      const float4 y0 = lyv[2 * tid];
      const float4 y1 = lyv[2 * tid + 1];
      const float yv[8] = {y0.x, y0.y, y0.z, y0.w, y1.x, y1.y, y1.z, y1.w};
      float yn[8];
#pragma unroll
      for (int j = 0; j < 8; ++j) {
        const float re = bctc + r0 * wct0[j] + r1 * wct1[j] + r2 * wct2[j];
        const float wvv = yv[j] - re;
        yn[j] = fmaxf(wvv - lam_n, 0.f) - fmaxf(-wvv - lam_n, 0.f);
      }

      if (!lastit) {
        const float4 l0 = lylv[2 * tid];
        const float4 l1 = lylv[2 * tid + 1];
        const float ylv[8] = {l0.x, l0.y, l0.z, l0.w, l1.x, l1.y, l1.z, l1.w};
        float4 s0, s1, m0, m1;
        s0.x = yn[0]; s0.y = yn[1]; s0.z = yn[2]; s0.w = yn[3];
        s1.x = yn[4]; s1.y = yn[5]; s1.z = yn[6]; s1.w = yn[7];
        m0.x = yn[0] + beta * (yn[0] - ylv[0]);
        m0.y = yn[1] + beta * (yn[1] - ylv[1]);
        m0.z = yn[2] + beta * (yn[2] - ylv[2]);
        m0.w = yn[3] + beta * (yn[3] - ylv[3]);
        m1.x = yn[4] + beta * (yn[4] - ylv[4]);
        m1.y = yn[5] + beta * (yn[5] - ylv[5]);
        m1.z = yn[6] + beta * (yn[6] - ylv[6]);
        m1.w = yn[7] + beta * (yn[7] - ylv[7]);
        lylv[2 * tid] = s0; lylv[2 * tid + 1] = s1;
        lyv[2 * tid]  = m0; lyv[2 * tid + 1]  = m1;
      } else {
        const int part = pbase >> 3;       // p>>3 constant over j
        const int qh = cell / 9;
        const int qw = cell - 9 * qh;
        const int ih = 8 * qh + part;
        float* op = out + ((n * 72 + ih) * 72 + 8 * qw) * 3 + c;
#pragma unroll
        for (int j = 0; j < 8; ++j) op[3 * j] = yn[j];
      }
    }
    __syncthreads();
  }
}

extern "C" void kernel_launch(void* const* d_in, const int* in_sizes, int n_in,
                              void* d_out, int out_size, void* d_ws, size_t ws_size,
                              hipStream_t stream) {
  const float* x      = (const float*)d_in[0];
  const float* lam    = (const float*)d_in[1];
  const float* w_conv = (const float*)d_in[2];
  const float* b_conv = (const float*)d_in[3];
  const float* w_ct   = (const float*)d_in[4];
  const float* b_ct   = (const float*)d_in[5];
  float* out = (float*)d_out;
  float* ws  = (float*)d_ws;  // needs ~595 KB

  hipLaunchKernelGGL(k0_init, dim3(80), dim3(256), 0, stream, w_conv, w_ct, ws);
  hipLaunchKernelGGL(fista_split, dim3(256), dim3(THREADS), 0, stream,
                     ws, x, lam, b_conv, b_ct, out);
}